// Round 4
// baseline (252.498 us; speedup 1.0000x reference)
//
#include <hip/hip_runtime.h>

#define B_ 4
#define C_ 256
#define N_ 4096
#define LOG2E 1.44269504088896340736f

typedef __attribute__((ext_vector_type(8))) short bf16x8;
typedef __attribute__((ext_vector_type(4))) float f32x4;

static __device__ __forceinline__ unsigned short f2bf(float f) {
    unsigned u = __builtin_bit_cast(unsigned, f);
    u += 0x7fffu + ((u >> 16) & 1u);
    return (unsigned short)(u >> 16);
}

static __device__ __forceinline__ float fexp2(float x) {
#if __has_builtin(__builtin_amdgcn_exp2f)
    return __builtin_amdgcn_exp2f(x);
#else
    return exp2f(x);
#endif
}

// ---------- k0: weight transpose (+ fold log2(e) into Wq) ----------
__global__ void k0_wprep(const float* __restrict__ Wq, const float* __restrict__ Wk,
                         const float* __restrict__ Wv, float* __restrict__ WqkT,
                         float* __restrict__ WvT) {
    int t = blockIdx.x * 256 + threadIdx.x;
    if (t < 256 * 64) {
        int c = t >> 6, o = t & 63;
        WqkT[t] = (o < 32) ? Wq[o * C_ + c] * LOG2E : Wk[(o - 32) * C_ + c];
    }
    int t2 = t - 256 * 64;
    if (t2 >= 0 && t2 < 256 * 256) {
        int cp = t2 >> 8, c = t2 & 255;
        WvT[t2] = Wv[c * C_ + cp];
    }
}

// ---------- k1: q/k prep -> bf16 [B][N][32]. 4 waves split c-range, LDS reduce ----
__global__ __launch_bounds__(256) void k1_qk(const float* __restrict__ x,
        const float* __restrict__ WqkT, const float* __restrict__ bq,
        const float* __restrict__ bk, unsigned short* __restrict__ qb,
        unsigned short* __restrict__ ktb) {
    __shared__ float red[4][64][33];
    int b = blockIdx.z, isk = blockIdx.y;
    int l = threadIdx.x & 63, v = threadIdx.x >> 6;
    int n = blockIdx.x * 64 + l;
    float acc[32];
#pragma unroll
    for (int o = 0; o < 32; ++o) acc[o] = 0.0f;
    const float* xp = x + (size_t)b * C_ * N_ + n;
    const float* wbase = WqkT + (isk ? 32 : 0);
#pragma unroll 4
    for (int c = 64 * v; c < 64 * v + 64; ++c) {
        float xv = xp[(size_t)c * N_];
        const float4* wr4 = (const float4*)(wbase + c * 64);  // uniform, 16B
#pragma unroll
        for (int o4 = 0; o4 < 8; ++o4) {
            float4 wv = wr4[o4];
            acc[4 * o4 + 0] += wv.x * xv;
            acc[4 * o4 + 1] += wv.y * xv;
            acc[4 * o4 + 2] += wv.z * xv;
            acc[4 * o4 + 3] += wv.w * xv;
        }
    }
#pragma unroll
    for (int o = 0; o < 32; ++o) red[v][l][o] = acc[o];
    __syncthreads();
    int nl = threadIdx.x & 63, ob = (threadIdx.x >> 6) * 8;
    const float* bias = isk ? bk : bq;
    float bs = isk ? 1.0f : LOG2E;
    unsigned pk[4];
#pragma unroll
    for (int i = 0; i < 4; ++i) {
        int o0 = ob + 2 * i, o1 = ob + 2 * i + 1;
        float v0 = red[0][nl][o0] + red[1][nl][o0] + red[2][nl][o0] + red[3][nl][o0] + bias[o0] * bs;
        float v1 = red[0][nl][o1] + red[1][nl][o1] + red[2][nl][o1] + red[3][nl][o1] + bias[o1] * bs;
        pk[i] = (unsigned)f2bf(v0) | ((unsigned)f2bf(v1) << 16);
    }
    unsigned short* dst = (isk ? ktb : qb) + ((size_t)b * N_ + blockIdx.x * 64 + nl) * 32 + ob;
    *(uint4*)dst = make_uint4(pk[0], pk[1], pk[2], pk[3]);
}

// ---------- k2: per-m Z-sums (no max needed: |S'| <= ~5). 8 waves split n-range ----
__global__ __launch_bounds__(512) void k2_stats(const unsigned short* __restrict__ qb,
        const unsigned short* __restrict__ ktb, float* __restrict__ Wcol) {
    __shared__ float red[64][33];
    int b = blockIdx.y;
    int m0 = blockIdx.x * 64;
    int lane = threadIdx.x & 63, w = threadIdx.x >> 6;
    int r16 = lane & 15, g = lane >> 4;
    const unsigned short* kb = ktb + ((size_t)b * N_ + m0 + r16) * 32 + 8 * g;
    bf16x8 kf0 = *(const bf16x8*)(kb);
    bf16x8 kf1 = *(const bf16x8*)(kb + 16 * 32);
    bf16x8 kf2 = *(const bf16x8*)(kb + 32 * 32);
    bf16x8 kf3 = *(const bf16x8*)(kb + 48 * 32);
    float z0 = 0, z1 = 0, z2 = 0, z3 = 0;
    const unsigned short* qbase = qb + ((size_t)b * N_ + w * 512 + r16) * 32 + 8 * g;
#pragma unroll 2
    for (int n0 = 0; n0 < 512; n0 += 16) {
        bf16x8 qf = *(const bf16x8*)(qbase + (size_t)n0 * 32);
        f32x4 d0 = __builtin_amdgcn_mfma_f32_16x16x32_bf16(qf, kf0, (f32x4){0, 0, 0, 0}, 0, 0, 0);
        f32x4 d1 = __builtin_amdgcn_mfma_f32_16x16x32_bf16(qf, kf1, (f32x4){0, 0, 0, 0}, 0, 0, 0);
        f32x4 d2 = __builtin_amdgcn_mfma_f32_16x16x32_bf16(qf, kf2, (f32x4){0, 0, 0, 0}, 0, 0, 0);
        f32x4 d3 = __builtin_amdgcn_mfma_f32_16x16x32_bf16(qf, kf3, (f32x4){0, 0, 0, 0}, 0, 0, 0);
        z0 += fexp2(d0[0]) + fexp2(d0[1]) + fexp2(d0[2]) + fexp2(d0[3]);
        z1 += fexp2(d1[0]) + fexp2(d1[1]) + fexp2(d1[2]) + fexp2(d1[3]);
        z2 += fexp2(d2[0]) + fexp2(d2[1]) + fexp2(d2[2]) + fexp2(d2[3]);
        z3 += fexp2(d3[0]) + fexp2(d3[1]) + fexp2(d3[2]) + fexp2(d3[3]);
    }
    red[r16][4 * w + g] = z0;
    red[16 + r16][4 * w + g] = z1;
    red[32 + r16][4 * w + g] = z2;
    red[48 + r16][4 * w + g] = z3;
    __syncthreads();
    if (threadIdx.x < 64) {
        float s = 0;
#pragma unroll
        for (int i = 0; i < 32; ++i) s += red[threadIdx.x][i];
        Wcol[(size_t)b * N_ + m0 + threadIdx.x] = 1.0f / s;
    }
}

// ---------- k3: v prep, pre-scaled by 1/Z: vtb[B][C][N] bf16 ----------
__global__ __launch_bounds__(256) void k3_v(const float* __restrict__ x,
        const float* __restrict__ WvT, const float* __restrict__ bv,
        const float* __restrict__ Wcol, unsigned short* __restrict__ vtb) {
    int b = blockIdx.z;
    int c0 = blockIdx.y * 32;
    int m = blockIdx.x * 256 + threadIdx.x;
    const float* xp = x + (size_t)b * C_ * N_ + m;
    float acc[32];
#pragma unroll
    for (int j = 0; j < 32; ++j) acc[j] = bv[c0 + j];
#pragma unroll 4
    for (int cp = 0; cp < C_; ++cp) {
        float xv = xp[(size_t)cp * N_];
        const float4* wr4 = (const float4*)(WvT + cp * C_ + c0);  // uniform, 16B
#pragma unroll
        for (int j4 = 0; j4 < 8; ++j4) {
            float4 wv = wr4[j4];
            acc[4 * j4 + 0] += wv.x * xv;
            acc[4 * j4 + 1] += wv.y * xv;
            acc[4 * j4 + 2] += wv.z * xv;
            acc[4 * j4 + 3] += wv.w * xv;
        }
    }
    float wm = Wcol[(size_t)b * N_ + m];
#pragma unroll
    for (int j = 0; j < 32; ++j)
        vtb[((size_t)b * C_ + c0 + j) * N_ + m] = f2bf(acc[j] * wm);
}

// ---------- k4: PV. c-split waves; V global->reg (no dup, no LDS); P dbuf LDS ----
// 8 waves: wave w owns c rows 32w..32w+31 (all 64 n). S computed once/block:
// wave w computes S^T for m-subtile ms=w>>1, n-half wn=w&1 (2 MFMAs) -> exp2 ->
// P dbuf (swizzled). One barrier/step. V,K prefetched 1 step ahead into regs.
__global__ __launch_bounds__(512) void k4_pv(const float* __restrict__ x,
        const unsigned short* __restrict__ qb, const unsigned short* __restrict__ ktb,
        const unsigned short* __restrict__ vtb,
        const float* __restrict__ gamma, float* __restrict__ out) {
    __shared__ unsigned short Pl[2][64 * 64];  // [buf][n][64m] byte-swizzled, 8KB each
    int b = blockIdx.y;
    int n0 = blockIdx.x * 64;
    int lane = threadIdx.x & 63, w = threadIdx.x >> 6;
    int ms = w >> 1, wn = w & 1;
    int r16 = lane & 15, g = lane >> 4;
    int swz = (r16 & 7) << 4;

    // S operands: q rows (n), k rows (m)
    const unsigned short* qbp = qb + ((size_t)b * N_ + n0 + 32 * wn + r16) * 32 + 8 * g;
    bf16x8 qf0 = *(const bf16x8*)(qbp);
    bf16x8 qf1 = *(const bf16x8*)(qbp + 16 * 32);
    const unsigned short* kbp = ktb + ((size_t)b * N_ + 16 * ms + r16) * 32 + 8 * g;
    // PV B-operand: V rows c = 32w + 16cs + r16, elems m = m0+32ks+8g..+7
    const unsigned short* vbp = vtb + ((size_t)b * C_ + 32 * w + r16) * N_ + 8 * g;

    // P write: rows 32wn+r16 (+16), byte col 32ms+8g, ^swz
    char* pwbase = (char*)&Pl[0][0] + (32 * wn + r16) * 128 + ((32 * ms + 8 * g) ^ swz);

    f32x4 acc[4][2];
#pragma unroll
    for (int i = 0; i < 4; ++i)
#pragma unroll
        for (int j = 0; j < 2; ++j) acc[i][j] = (f32x4){0, 0, 0, 0};

    // prologue: load ka(0), vb(0); compute S(0) -> P[0]
    bf16x8 ka = *(const bf16x8*)(kbp);
    bf16x8 vb[2][2], vbn[2][2];
#pragma unroll
    for (int cs = 0; cs < 2; ++cs)
#pragma unroll
        for (int ks = 0; ks < 2; ++ks)
            vb[cs][ks] = *(const bf16x8*)(vbp + (size_t)cs * 16 * N_ + 32 * ks);
    {
        f32x4 s0 = __builtin_amdgcn_mfma_f32_16x16x32_bf16(ka, qf0, (f32x4){0, 0, 0, 0}, 0, 0, 0);
        f32x4 s1 = __builtin_amdgcn_mfma_f32_16x16x32_bf16(ka, qf1, (f32x4){0, 0, 0, 0}, 0, 0, 0);
        unsigned a0 = (unsigned)f2bf(fexp2(s0[0])) | ((unsigned)f2bf(fexp2(s0[1])) << 16);
        unsigned a1 = (unsigned)f2bf(fexp2(s0[2])) | ((unsigned)f2bf(fexp2(s0[3])) << 16);
        unsigned a2 = (unsigned)f2bf(fexp2(s1[0])) | ((unsigned)f2bf(fexp2(s1[1])) << 16);
        unsigned a3 = (unsigned)f2bf(fexp2(s1[2])) | ((unsigned)f2bf(fexp2(s1[3])) << 16);
        *(uint2*)(pwbase) = make_uint2(a0, a1);
        *(uint2*)(pwbase + 16 * 128) = make_uint2(a2, a3);
    }
    __syncthreads();

#pragma unroll 2
    for (int t = 0; t < 64; ++t) {
        int cbuf = t & 1;
        // prefetch t+1 operands (in flight during PV)
        bf16x8 kan = ka;
        if (t < 63) {
            size_t m1 = (size_t)(t + 1) * 64;
            kan = *(const bf16x8*)(kbp + m1 * 32);
#pragma unroll
            for (int cs = 0; cs < 2; ++cs)
#pragma unroll
                for (int ks = 0; ks < 2; ++ks)
                    vbn[cs][ks] = *(const bf16x8*)(vbp + (size_t)cs * 16 * N_ + m1 + 32 * ks);
        }
        // read P(t) fragments, 16 PV MFMAs
        const char* prd = (const char*)&Pl[cbuf][0] + r16 * 128;
        bf16x8 pa[4][2];
#pragma unroll
        for (int ns = 0; ns < 4; ++ns)
#pragma unroll
            for (int ks = 0; ks < 2; ++ks)
                pa[ns][ks] = *(const bf16x8*)(prd + ns * 16 * 128 + ((64 * ks + 16 * g) ^ swz));
#pragma unroll
        for (int ns = 0; ns < 4; ++ns)
#pragma unroll
            for (int cs = 0; cs < 2; ++cs)
#pragma unroll
                for (int ks = 0; ks < 2; ++ks)
                    acc[ns][cs] = __builtin_amdgcn_mfma_f32_16x16x32_bf16(
                        pa[ns][ks], vb[cs][ks], acc[ns][cs], 0, 0, 0);
        // compute S(t+1) -> P[buf^1]
        if (t < 63) {
            f32x4 s0 = __builtin_amdgcn_mfma_f32_16x16x32_bf16(kan, qf0, (f32x4){0, 0, 0, 0}, 0, 0, 0);
            f32x4 s1 = __builtin_amdgcn_mfma_f32_16x16x32_bf16(kan, qf1, (f32x4){0, 0, 0, 0}, 0, 0, 0);
            unsigned a0 = (unsigned)f2bf(fexp2(s0[0])) | ((unsigned)f2bf(fexp2(s0[1])) << 16);
            unsigned a1 = (unsigned)f2bf(fexp2(s0[2])) | ((unsigned)f2bf(fexp2(s0[3])) << 16);
            unsigned a2 = (unsigned)f2bf(fexp2(s1[0])) | ((unsigned)f2bf(fexp2(s1[1])) << 16);
            unsigned a3 = (unsigned)f2bf(fexp2(s1[2])) | ((unsigned)f2bf(fexp2(s1[3])) << 16);
            char* pw = pwbase + (cbuf ^ 1) * 8192;
            *(uint2*)(pw) = make_uint2(a0, a1);
            *(uint2*)(pw + 16 * 128) = make_uint2(a2, a3);
        }
        __syncthreads();
        ka = kan;
#pragma unroll
        for (int cs = 0; cs < 2; ++cs)
#pragma unroll
            for (int ks = 0; ks < 2; ++ks) vb[cs][ks] = vbn[cs][ks];
    }

    float gm = gamma[0];
#pragma unroll
    for (int ns = 0; ns < 4; ++ns)
#pragma unroll
        for (int cs = 0; cs < 2; ++cs) {
            size_t c = 32 * w + 16 * cs + r16;
            size_t idx = ((size_t)b * C_ + c) * N_ + n0 + 16 * ns + 4 * g;
            float4 xv = *(const float4*)(x + idx);
            float4 o;
            o.x = gm * acc[ns][cs][0] + xv.x;
            o.y = gm * acc[ns][cs][1] + xv.y;
            o.z = gm * acc[ns][cs][2] + xv.z;
            o.w = gm * acc[ns][cs][3] + xv.w;
            *(float4*)(out + idx) = o;
        }
}

extern "C" void kernel_launch(void* const* d_in, const int* in_sizes, int n_in,
                              void* d_out, int out_size, void* d_ws, size_t ws_size,
                              hipStream_t stream) {
    const float* x = (const float*)d_in[0];
    const float* Wq = (const float*)d_in[1];
    const float* bq = (const float*)d_in[2];
    const float* Wk = (const float*)d_in[3];
    const float* bk = (const float*)d_in[4];
    const float* Wv = (const float*)d_in[5];
    const float* bv = (const float*)d_in[6];
    const float* gamma = (const float*)d_in[7];
    float* out = (float*)d_out;

    char* ws = (char*)d_ws;
    unsigned short* qb  = (unsigned short*)(ws);                     // 1 MiB
    unsigned short* ktb = (unsigned short*)(ws + (1u << 20));        // 1 MiB
    unsigned short* vtb = (unsigned short*)(ws + (2u << 20));        // 8 MiB
    float* Wcol = (float*)(ws + (10u << 20));                        // 64 KiB
    float* WqkT = (float*)(ws + (10u << 20) + (1u << 16));           // 64 KiB
    float* WvT  = (float*)(ws + (10u << 20) + (2u << 16));           // 256 KiB

    k0_wprep<<<320, 256, 0, stream>>>(Wq, Wk, Wv, WqkT, WvT);
    k1_qk<<<dim3(N_ / 64, 2, B_), 256, 0, stream>>>(x, WqkT, bq, bk, qb, ktb);
    k2_stats<<<dim3(N_ / 64, B_), 512, 0, stream>>>(qb, ktb, Wcol);
    k3_v<<<dim3(N_ / 256, C_ / 32, B_), 256, 0, stream>>>(x, WvT, bv, Wcol, vtb);
    k4_pv<<<dim3(N_ / 64, B_), 512, 0, stream>>>(x, qb, ktb, vtb, gamma, out);
}

// Round 6
// 238.495 us; speedup vs baseline: 1.0587x; 1.0587x over previous
//
#include <hip/hip_runtime.h>

#define B_ 4
#define C_ 256
#define N_ 4096
#define LOG2E 1.44269504088896340736f

typedef __attribute__((ext_vector_type(8))) short bf16x8;
typedef __attribute__((ext_vector_type(4))) float f32x4;

static __device__ __forceinline__ unsigned short f2bf(float f) {
    unsigned u = __builtin_bit_cast(unsigned, f);
    u += 0x7fffu + ((u >> 16) & 1u);
    return (unsigned short)(u >> 16);
}

static __device__ __forceinline__ float fexp2(float x) {
#if __has_builtin(__builtin_amdgcn_exp2f)
    return __builtin_amdgcn_exp2f(x);
#else
    return exp2f(x);
#endif
}

// barrier that drains only LDS ops; register-destined global loads stay in flight
#define LDS_BARRIER() asm volatile("s_waitcnt lgkmcnt(0)\n\ts_barrier" ::: "memory")

// ---------- k0: WqkT fp32 [256c][64o] (q cols pre-scaled by log2e) + Wv bf16 cast ----
__global__ void k0_wprep(const float* __restrict__ Wq, const float* __restrict__ Wk,
                         const float* __restrict__ Wv, float* __restrict__ WqkT,
                         unsigned short* __restrict__ wvb) {
    int t = blockIdx.x * 256 + threadIdx.x;
    if (t < 256 * 64) {
        int c = t >> 6, o = t & 63;
        WqkT[t] = (o < 32) ? Wq[o * C_ + c] * LOG2E : Wk[(o - 32) * C_ + c];
    }
    int t2 = t - 256 * 64;
    if (t2 >= 0 && t2 < 256 * 256) wvb[t2] = f2bf(Wv[t2]);
}

// ---------- k1: one x-pass -> q,k bf16 [B][N][32] AND xb = bf16(x) [B][C][N] ------
__global__ __launch_bounds__(256) void k1_qkx(const float* __restrict__ x,
        const float* __restrict__ WqkT, const float* __restrict__ bq,
        const float* __restrict__ bk, unsigned short* __restrict__ qb,
        unsigned short* __restrict__ ktb, unsigned short* __restrict__ xb) {
    __shared__ float red[4][64][64];
    int b = blockIdx.y;
    int n0 = blockIdx.x * 64;
    int l = threadIdx.x & 63, v = threadIdx.x >> 6;
    const float* xp = x + (size_t)b * C_ * N_ + n0 + l;
    unsigned short* xbp = xb + (size_t)b * C_ * N_ + n0 + l;
    float acc[64];
#pragma unroll
    for (int o = 0; o < 64; ++o) acc[o] = 0.0f;
    for (int c = 64 * v; c < 64 * v + 64; ++c) {
        float xv = xp[(size_t)c * N_];
        xbp[(size_t)c * N_] = f2bf(xv);
        const float4* wr4 = (const float4*)(WqkT + c * 64);  // uniform -> scalar loads
#pragma unroll
        for (int o4 = 0; o4 < 16; ++o4) {
            float4 wv = wr4[o4];
            acc[4 * o4 + 0] += wv.x * xv;
            acc[4 * o4 + 1] += wv.y * xv;
            acc[4 * o4 + 2] += wv.z * xv;
            acc[4 * o4 + 3] += wv.w * xv;
        }
    }
#pragma unroll
    for (int o = 0; o < 64; ++o) red[v][l][o] = acc[o];
    __syncthreads();
    int n = threadIdx.x & 63, og = threadIdx.x >> 6;  // og 0,1 -> q ; 2,3 -> k
    int o0 = og * 16;
    unsigned pk[8];
#pragma unroll
    for (int i = 0; i < 8; ++i) {
        int oa = o0 + 2 * i, ob = oa + 1;
        float va = red[0][n][oa] + red[1][n][oa] + red[2][n][oa] + red[3][n][oa];
        float vb = red[0][n][ob] + red[1][n][ob] + red[2][n][ob] + red[3][n][ob];
        if (og < 2) { va += bq[oa] * LOG2E; vb += bq[ob] * LOG2E; }
        else        { va += bk[oa - 32];    vb += bk[ob - 32]; }
        pk[i] = (unsigned)f2bf(va) | ((unsigned)f2bf(vb) << 16);
    }
    unsigned short* dst = (og < 2)
        ? qb + ((size_t)b * N_ + n0 + n) * 32 + o0
        : ktb + ((size_t)b * N_ + n0 + n) * 32 + (o0 - 32);
    ((uint4*)dst)[0] = make_uint4(pk[0], pk[1], pk[2], pk[3]);
    ((uint4*)dst)[1] = make_uint4(pk[4], pk[5], pk[6], pk[7]);
}

// ---------- k2: per-m Z-sums (|S'| small -> no max-sub). 8 waves split n-range ----
__global__ __launch_bounds__(512) void k2_stats(const unsigned short* __restrict__ qb,
        const unsigned short* __restrict__ ktb, float* __restrict__ Wcol) {
    __shared__ float red[64][33];
    int b = blockIdx.y;
    int m0 = blockIdx.x * 64;
    int lane = threadIdx.x & 63, w = threadIdx.x >> 6;
    int r16 = lane & 15, g = lane >> 4;
    const unsigned short* kb = ktb + ((size_t)b * N_ + m0 + r16) * 32 + 8 * g;
    bf16x8 kf0 = *(const bf16x8*)(kb);
    bf16x8 kf1 = *(const bf16x8*)(kb + 16 * 32);
    bf16x8 kf2 = *(const bf16x8*)(kb + 32 * 32);
    bf16x8 kf3 = *(const bf16x8*)(kb + 48 * 32);
    float z0 = 0, z1 = 0, z2 = 0, z3 = 0;
    const unsigned short* qbase = qb + ((size_t)b * N_ + w * 512 + r16) * 32 + 8 * g;
#pragma unroll 2
    for (int n0 = 0; n0 < 512; n0 += 16) {
        bf16x8 qf = *(const bf16x8*)(qbase + (size_t)n0 * 32);
        f32x4 d0 = __builtin_amdgcn_mfma_f32_16x16x32_bf16(qf, kf0, (f32x4){0, 0, 0, 0}, 0, 0, 0);
        f32x4 d1 = __builtin_amdgcn_mfma_f32_16x16x32_bf16(qf, kf1, (f32x4){0, 0, 0, 0}, 0, 0, 0);
        f32x4 d2 = __builtin_amdgcn_mfma_f32_16x16x32_bf16(qf, kf2, (f32x4){0, 0, 0, 0}, 0, 0, 0);
        f32x4 d3 = __builtin_amdgcn_mfma_f32_16x16x32_bf16(qf, kf3, (f32x4){0, 0, 0, 0}, 0, 0, 0);
        z0 += fexp2(d0[0]) + fexp2(d0[1]) + fexp2(d0[2]) + fexp2(d0[3]);
        z1 += fexp2(d1[0]) + fexp2(d1[1]) + fexp2(d1[2]) + fexp2(d1[3]);
        z2 += fexp2(d2[0]) + fexp2(d2[1]) + fexp2(d2[2]) + fexp2(d2[3]);
        z3 += fexp2(d3[0]) + fexp2(d3[1]) + fexp2(d3[2]) + fexp2(d3[3]);
    }
    red[r16][4 * w + g] = z0;
    red[16 + r16][4 * w + g] = z1;
    red[32 + r16][4 * w + g] = z2;
    red[48 + r16][4 * w + g] = z3;
    __syncthreads();
    if (threadIdx.x < 64) {
        float s = 0;
#pragma unroll
        for (int i = 0; i < 32; ++i) s += red[threadIdx.x][i];
        Wcol[(size_t)b * N_ + m0 + threadIdx.x] = 1.0f / s;
    }
}

// ---------- k4: Y[n][cp] = sum_m P'[n][m] * xb[cp][m], plus rowP[n] = sum_m P' ----
// Identical schedule to old PV (vtb -> xb), but: P' = exp2(S')*invZ[m] folded here,
// LDS-only barrier (global prefetches stay in flight across it), Yt bf16 out.
__global__ __launch_bounds__(512) void k4_y(const unsigned short* __restrict__ qb,
        const unsigned short* __restrict__ ktb, const unsigned short* __restrict__ xb,
        const float* __restrict__ Wcol, unsigned short* __restrict__ Yt,
        float* __restrict__ rowP) {
    __shared__ unsigned short Pl[2][64 * 64];  // [buf][n][64m] byte-swizzled
    __shared__ float rpl[4][64];
    int b = blockIdx.y;
    int n0 = blockIdx.x * 64;
    int lane = threadIdx.x & 63, w = threadIdx.x >> 6;
    int ms = w >> 1, wn = w & 1;
    int r16 = lane & 15, g = lane >> 4;
    int swz = (r16 & 7) << 4;

    const unsigned short* qbp = qb + ((size_t)b * N_ + n0 + 32 * wn + r16) * 32 + 8 * g;
    bf16x8 qf0 = *(const bf16x8*)(qbp);
    bf16x8 qf1 = *(const bf16x8*)(qbp + 16 * 32);
    const unsigned short* kbp = ktb + ((size_t)b * N_ + 16 * ms + r16) * 32 + 8 * g;
    const unsigned short* xbp = xb + ((size_t)b * C_ + 32 * w + r16) * N_ + 8 * g;
    const float* izp = Wcol + (size_t)b * N_ + 16 * ms + 4 * g;

    char* pwbase = (char*)&Pl[0][0] + (32 * wn + r16) * 128 + ((32 * ms + 8 * g) ^ swz);

    f32x4 acc[4][2];
#pragma unroll
    for (int i = 0; i < 4; ++i)
#pragma unroll
        for (int j = 0; j < 2; ++j) acc[i][j] = (f32x4){0, 0, 0, 0};
    float rp0 = 0.0f, rp1 = 0.0f;

    bf16x8 ka = *(const bf16x8*)(kbp);
    bf16x8 xf[2][2], xfn[2][2];
#pragma unroll
    for (int cs = 0; cs < 2; ++cs)
#pragma unroll
        for (int ks = 0; ks < 2; ++ks)
            xf[cs][ks] = *(const bf16x8*)(xbp + (size_t)cs * 16 * N_ + 32 * ks);
    float4 iz = *(const float4*)(izp);
    {
        f32x4 s0 = __builtin_amdgcn_mfma_f32_16x16x32_bf16(ka, qf0, (f32x4){0, 0, 0, 0}, 0, 0, 0);
        f32x4 s1 = __builtin_amdgcn_mfma_f32_16x16x32_bf16(ka, qf1, (f32x4){0, 0, 0, 0}, 0, 0, 0);
        float p00 = fexp2(s0[0]) * iz.x, p01 = fexp2(s0[1]) * iz.y;
        float p02 = fexp2(s0[2]) * iz.z, p03 = fexp2(s0[3]) * iz.w;
        float p10 = fexp2(s1[0]) * iz.x, p11 = fexp2(s1[1]) * iz.y;
        float p12 = fexp2(s1[2]) * iz.z, p13 = fexp2(s1[3]) * iz.w;
        rp0 += p00 + p01 + p02 + p03;
        rp1 += p10 + p11 + p12 + p13;
        *(uint2*)(pwbase) = make_uint2(
            (unsigned)f2bf(p00) | ((unsigned)f2bf(p01) << 16),
            (unsigned)f2bf(p02) | ((unsigned)f2bf(p03) << 16));
        *(uint2*)(pwbase + 16 * 128) = make_uint2(
            (unsigned)f2bf(p10) | ((unsigned)f2bf(p11) << 16),
            (unsigned)f2bf(p12) | ((unsigned)f2bf(p13) << 16));
    }
    LDS_BARRIER();

#pragma unroll 2
    for (int t = 0; t < 64; ++t) {
        int cbuf = t & 1;
        bf16x8 kan = ka;
        float4 izn = iz;
        if (t < 63) {
            size_t m1 = (size_t)(t + 1) * 64;
            kan = *(const bf16x8*)(kbp + m1 * 32);
            izn = *(const float4*)(izp + m1);
#pragma unroll
            for (int cs = 0; cs < 2; ++cs)
#pragma unroll
                for (int ks = 0; ks < 2; ++ks)
                    xfn[cs][ks] = *(const bf16x8*)(xbp + (size_t)cs * 16 * N_ + m1 + 32 * ks);
        }
        const char* prd = (const char*)&Pl[cbuf][0] + r16 * 128;
        bf16x8 pa[4][2];
#pragma unroll
        for (int ns = 0; ns < 4; ++ns)
#pragma unroll
            for (int ks = 0; ks < 2; ++ks)
                pa[ns][ks] = *(const bf16x8*)(prd + ns * 16 * 128 + ((64 * ks + 16 * g) ^ swz));
#pragma unroll
        for (int ns = 0; ns < 4; ++ns)
#pragma unroll
            for (int cs = 0; cs < 2; ++cs)
#pragma unroll
                for (int ks = 0; ks < 2; ++ks)
                    acc[ns][cs] = __builtin_amdgcn_mfma_f32_16x16x32_bf16(
                        pa[ns][ks], xf[cs][ks], acc[ns][cs], 0, 0, 0);
        if (t < 63) {
            f32x4 s0 = __builtin_amdgcn_mfma_f32_16x16x32_bf16(kan, qf0, (f32x4){0, 0, 0, 0}, 0, 0, 0);
            f32x4 s1 = __builtin_amdgcn_mfma_f32_16x16x32_bf16(kan, qf1, (f32x4){0, 0, 0, 0}, 0, 0, 0);
            float p00 = fexp2(s0[0]) * izn.x, p01 = fexp2(s0[1]) * izn.y;
            float p02 = fexp2(s0[2]) * izn.z, p03 = fexp2(s0[3]) * izn.w;
            float p10 = fexp2(s1[0]) * izn.x, p11 = fexp2(s1[1]) * izn.y;
            float p12 = fexp2(s1[2]) * izn.z, p13 = fexp2(s1[3]) * izn.w;
            rp0 += p00 + p01 + p02 + p03;
            rp1 += p10 + p11 + p12 + p13;
            char* pw = pwbase + (cbuf ^ 1) * 8192;
            *(uint2*)(pw) = make_uint2(
                (unsigned)f2bf(p00) | ((unsigned)f2bf(p01) << 16),
                (unsigned)f2bf(p02) | ((unsigned)f2bf(p03) << 16));
            *(uint2*)(pw + 16 * 128) = make_uint2(
                (unsigned)f2bf(p10) | ((unsigned)f2bf(p11) << 16),
                (unsigned)f2bf(p12) | ((unsigned)f2bf(p13) << 16));
        }
        LDS_BARRIER();
        ka = kan;
        iz = izn;
#pragma unroll
        for (int cs = 0; cs < 2; ++cs)
#pragma unroll
            for (int ks = 0; ks < 2; ++ks) xf[cs][ks] = xfn[cs][ks];
    }

    // rowP reduce: sum over g (shfl) then over ms (LDS)
    rp0 += __shfl_xor(rp0, 16); rp0 += __shfl_xor(rp0, 32);
    rp1 += __shfl_xor(rp1, 16); rp1 += __shfl_xor(rp1, 32);
    if (g == 0) {
        rpl[ms][32 * wn + r16] = rp0;
        rpl[ms][32 * wn + 16 + r16] = rp1;
    }
    __syncthreads();
    if (threadIdx.x < 64)
        rowP[(size_t)b * N_ + n0 + threadIdx.x] =
            rpl[0][threadIdx.x] + rpl[1][threadIdx.x] + rpl[2][threadIdx.x] + rpl[3][threadIdx.x];

    // Yt[b][n][cp] bf16 stores (2B scatter, epilogue-only)
#pragma unroll
    for (int ns = 0; ns < 4; ++ns)
#pragma unroll
        for (int cs = 0; cs < 2; ++cs) {
            int cp = 32 * w + 16 * cs + r16;
            f32x4 a = acc[ns][cs];
#pragma unroll
            for (int r = 0; r < 4; ++r) {
                int n = n0 + 16 * ns + 4 * g + r;
                Yt[((size_t)b * N_ + n) * C_ + cp] = f2bf(a[r]);
            }
        }
}

// ---------- k5: out[c][n] = gamma*(Wv·Y[n] + rowP[n]*bv[c]) + x[c][n] -------------
__global__ __launch_bounds__(256) void k5_out(const float* __restrict__ x,
        const unsigned short* __restrict__ wvb, const unsigned short* __restrict__ Yt,
        const float* __restrict__ rowP, const float* __restrict__ bv,
        const float* __restrict__ gamma, float* __restrict__ out) {
    int b = blockIdx.y;
    int n0 = blockIdx.x * 32;
    int lane = threadIdx.x & 63, w = threadIdx.x >> 6;
    int r16 = lane & 15, g = lane >> 4;
    const unsigned short* wvp = wvb + (64 * w + r16) * C_ + 8 * g;
    const unsigned short* ytp = Yt + ((size_t)b * N_ + n0 + r16) * C_ + 8 * g;

    f32x4 acc[4][2];  // [cs][ns]
#pragma unroll
    for (int i = 0; i < 4; ++i)
#pragma unroll
        for (int j = 0; j < 2; ++j) acc[i][j] = (f32x4){0, 0, 0, 0};

#pragma unroll
    for (int kc = 0; kc < 8; ++kc) {
        bf16x8 yf[2];
#pragma unroll
        for (int ns = 0; ns < 2; ++ns)
            yf[ns] = *(const bf16x8*)(ytp + ns * 16 * C_ + kc * 32);
#pragma unroll
        for (int cs = 0; cs < 4; ++cs) {
            bf16x8 wf = *(const bf16x8*)(wvp + cs * 16 * C_ + kc * 32);
#pragma unroll
            for (int ns = 0; ns < 2; ++ns)
                acc[cs][ns] = __builtin_amdgcn_mfma_f32_16x16x32_bf16(
                    wf, yf[ns], acc[cs][ns], 0, 0, 0);
        }
    }
    float gm = gamma[0];
    float rpv[2];
#pragma unroll
    for (int ns = 0; ns < 2; ++ns) rpv[ns] = rowP[(size_t)b * N_ + n0 + 16 * ns + r16];
#pragma unroll
    for (int cs = 0; cs < 4; ++cs) {
        float4 bvv = *(const float4*)(bv + 64 * w + 16 * cs + 4 * g);
        float bva[4] = {bvv.x, bvv.y, bvv.z, bvv.w};
#pragma unroll
        for (int ns = 0; ns < 2; ++ns)
#pragma unroll
            for (int r = 0; r < 4; ++r) {
                int c = 64 * w + 16 * cs + 4 * g + r;
                int n = n0 + 16 * ns + r16;
                size_t idx = ((size_t)b * C_ + c) * N_ + n;
                out[idx] = gm * (acc[cs][ns][r] + rpv[ns] * bva[r]) + x[idx];
            }
    }
}

extern "C" void kernel_launch(void* const* d_in, const int* in_sizes, int n_in,
                              void* d_out, int out_size, void* d_ws, size_t ws_size,
                              hipStream_t stream) {
    const float* x = (const float*)d_in[0];
    const float* Wq = (const float*)d_in[1];
    const float* bq = (const float*)d_in[2];
    const float* Wk = (const float*)d_in[3];
    const float* bk = (const float*)d_in[4];
    const float* Wv = (const float*)d_in[5];
    const float* bv = (const float*)d_in[6];
    const float* gamma = (const float*)d_in[7];
    float* out = (float*)d_out;

    char* ws = (char*)d_ws;
    unsigned short* qb  = (unsigned short*)(ws);                       // 1 MiB
    unsigned short* ktb = (unsigned short*)(ws + (1u << 20));          // 1 MiB
    unsigned short* xb  = (unsigned short*)(ws + (2u << 20));          // 8 MiB
    unsigned short* Yt  = (unsigned short*)(ws + (10u << 20));         // 8 MiB
    float* Wcol = (float*)(ws + (18u << 20));                          // 64 KiB
    float* WqkT = (float*)(ws + (18u << 20) + (1u << 16));             // 64 KiB
    unsigned short* wvb = (unsigned short*)(ws + (18u << 20) + (2u << 16)); // 128 KiB
    float* rowP = (float*)(ws + (18u << 20) + (4u << 16));             // 64 KiB

    k0_wprep<<<320, 256, 0, stream>>>(Wq, Wk, Wv, WqkT, wvb);
    k1_qkx<<<dim3(N_ / 64, B_), 256, 0, stream>>>(x, WqkT, bq, bk, qb, ktb, xb);
    k2_stats<<<dim3(N_ / 64, B_), 512, 0, stream>>>(qb, ktb, Wcol);
    k4_y<<<dim3(N_ / 64, B_), 512, 0, stream>>>(qb, ktb, xb, Wcol, Yt, rowP);
    k5_out<<<dim3(N_ / 32, B_), 256, 0, stream>>>(x, wvb, Yt, rowP, bv, gamma, out);
}

// Round 7
// 228.364 us; speedup vs baseline: 1.1057x; 1.0444x over previous
//
#include <hip/hip_runtime.h>

#define B_ 4
#define C_ 256
#define N_ 4096
#define LOG2E 1.44269504088896340736f

typedef __attribute__((ext_vector_type(8))) short bf16x8;
typedef __attribute__((ext_vector_type(4))) float f32x4;

static __device__ __forceinline__ unsigned short f2bf(float f) {
    unsigned u = __builtin_bit_cast(unsigned, f);
    u += 0x7fffu + ((u >> 16) & 1u);
    return (unsigned short)(u >> 16);
}

static __device__ __forceinline__ float fexp2(float x) {
#if __has_builtin(__builtin_amdgcn_exp2f)
    return __builtin_amdgcn_exp2f(x);
#else
    return exp2f(x);
#endif
}

// barrier that drains only LDS ops; register-destined global loads stay in flight
#define LDS_BARRIER() asm volatile("s_waitcnt lgkmcnt(0)\n\ts_barrier" ::: "memory")

// ---------- k0: WqkT fp32 [256c][64o] (q cols pre-scaled by log2e) + Wv bf16 cast ----
__global__ void k0_wprep(const float* __restrict__ Wq, const float* __restrict__ Wk,
                         const float* __restrict__ Wv, float* __restrict__ WqkT,
                         unsigned short* __restrict__ wvb) {
    int t = blockIdx.x * 256 + threadIdx.x;
    if (t < 256 * 64) {
        int c = t >> 6, o = t & 63;
        WqkT[t] = (o < 32) ? Wq[o * C_ + c] * LOG2E : Wk[(o - 32) * C_ + c];
    }
    int t2 = t - 256 * 64;
    if (t2 >= 0 && t2 < 256 * 256) wvb[t2] = f2bf(Wv[t2]);
}

// ---------- k1: one x-pass -> q,k bf16 [B][N][32] AND xb = bf16(x) [B][C][N] ------
__global__ __launch_bounds__(256) void k1_qkx(const float* __restrict__ x,
        const float* __restrict__ WqkT, const float* __restrict__ bq,
        const float* __restrict__ bk, unsigned short* __restrict__ qb,
        unsigned short* __restrict__ ktb, unsigned short* __restrict__ xb) {
    __shared__ float red[4][64][64];
    int b = blockIdx.y;
    int n0 = blockIdx.x * 64;
    int l = threadIdx.x & 63, v = threadIdx.x >> 6;
    const float* xp = x + (size_t)b * C_ * N_ + n0 + l;
    unsigned short* xbp = xb + (size_t)b * C_ * N_ + n0 + l;
    float acc[64];
#pragma unroll
    for (int o = 0; o < 64; ++o) acc[o] = 0.0f;
    for (int c = 64 * v; c < 64 * v + 64; ++c) {
        float xv = xp[(size_t)c * N_];
        xbp[(size_t)c * N_] = f2bf(xv);
        const float4* wr4 = (const float4*)(WqkT + c * 64);  // uniform -> scalar loads
#pragma unroll
        for (int o4 = 0; o4 < 16; ++o4) {
            float4 wv = wr4[o4];
            acc[4 * o4 + 0] += wv.x * xv;
            acc[4 * o4 + 1] += wv.y * xv;
            acc[4 * o4 + 2] += wv.z * xv;
            acc[4 * o4 + 3] += wv.w * xv;
        }
    }
#pragma unroll
    for (int o = 0; o < 64; ++o) red[v][l][o] = acc[o];
    __syncthreads();
    int n = threadIdx.x & 63, og = threadIdx.x >> 6;  // og 0,1 -> q ; 2,3 -> k
    int o0 = og * 16;
    unsigned pk[8];
#pragma unroll
    for (int i = 0; i < 8; ++i) {
        int oa = o0 + 2 * i, ob = oa + 1;
        float va = red[0][n][oa] + red[1][n][oa] + red[2][n][oa] + red[3][n][oa];
        float vb = red[0][n][ob] + red[1][n][ob] + red[2][n][ob] + red[3][n][ob];
        if (og < 2) { va += bq[oa] * LOG2E; vb += bq[ob] * LOG2E; }
        else        { va += bk[oa - 32];    vb += bk[ob - 32]; }
        pk[i] = (unsigned)f2bf(va) | ((unsigned)f2bf(vb) << 16);
    }
    unsigned short* dst = (og < 2)
        ? qb + ((size_t)b * N_ + n0 + n) * 32 + o0
        : ktb + ((size_t)b * N_ + n0 + n) * 32 + (o0 - 32);
    ((uint4*)dst)[0] = make_uint4(pk[0], pk[1], pk[2], pk[3]);
    ((uint4*)dst)[1] = make_uint4(pk[4], pk[5], pk[6], pk[7]);
}

// ---------- k2: per-m Z-sums (|S'| small -> no max-sub). 8 waves split n-range ----
__global__ __launch_bounds__(512) void k2_stats(const unsigned short* __restrict__ qb,
        const unsigned short* __restrict__ ktb, float* __restrict__ Wcol) {
    __shared__ float red[64][33];
    int b = blockIdx.y;
    int m0 = blockIdx.x * 64;
    int lane = threadIdx.x & 63, w = threadIdx.x >> 6;
    int r16 = lane & 15, g = lane >> 4;
    const unsigned short* kb = ktb + ((size_t)b * N_ + m0 + r16) * 32 + 8 * g;
    bf16x8 kf0 = *(const bf16x8*)(kb);
    bf16x8 kf1 = *(const bf16x8*)(kb + 16 * 32);
    bf16x8 kf2 = *(const bf16x8*)(kb + 32 * 32);
    bf16x8 kf3 = *(const bf16x8*)(kb + 48 * 32);
    float z0 = 0, z1 = 0, z2 = 0, z3 = 0;
    const unsigned short* qbase = qb + ((size_t)b * N_ + w * 512 + r16) * 32 + 8 * g;
#pragma unroll 2
    for (int n0 = 0; n0 < 512; n0 += 16) {
        bf16x8 qf = *(const bf16x8*)(qbase + (size_t)n0 * 32);
        f32x4 d0 = __builtin_amdgcn_mfma_f32_16x16x32_bf16(qf, kf0, (f32x4){0, 0, 0, 0}, 0, 0, 0);
        f32x4 d1 = __builtin_amdgcn_mfma_f32_16x16x32_bf16(qf, kf1, (f32x4){0, 0, 0, 0}, 0, 0, 0);
        f32x4 d2 = __builtin_amdgcn_mfma_f32_16x16x32_bf16(qf, kf2, (f32x4){0, 0, 0, 0}, 0, 0, 0);
        f32x4 d3 = __builtin_amdgcn_mfma_f32_16x16x32_bf16(qf, kf3, (f32x4){0, 0, 0, 0}, 0, 0, 0);
        z0 += fexp2(d0[0]) + fexp2(d0[1]) + fexp2(d0[2]) + fexp2(d0[3]);
        z1 += fexp2(d1[0]) + fexp2(d1[1]) + fexp2(d1[2]) + fexp2(d1[3]);
        z2 += fexp2(d2[0]) + fexp2(d2[1]) + fexp2(d2[2]) + fexp2(d2[3]);
        z3 += fexp2(d3[0]) + fexp2(d3[1]) + fexp2(d3[2]) + fexp2(d3[3]);
    }
    red[r16][4 * w + g] = z0;
    red[16 + r16][4 * w + g] = z1;
    red[32 + r16][4 * w + g] = z2;
    red[48 + r16][4 * w + g] = z3;
    __syncthreads();
    if (threadIdx.x < 64) {
        float s = 0;
#pragma unroll
        for (int i = 0; i < 32; ++i) s += red[threadIdx.x][i];
        Wcol[(size_t)b * N_ + m0 + threadIdx.x] = 1.0f / s;
    }
}

// ---------- k4: Y[n][cp] = sum_m P'[n][m]*xb[cp][m]; rowP[n] = sum_m P' ----------
// P TRIPLE-buffered: step t reads P[t%3], writes S(t+2) into P[(t+2)%3] -> the
// S chain (global ka/iz load -> exp2 -> ds_write) has 2 barriers of slack and
// leaves the critical path. All operand loads via 3-deep NAMED register queues
// (compile-time indices, 3-step latency cover). One LDS-only barrier per step.
__global__ __launch_bounds__(512) void k4_y(const unsigned short* __restrict__ qb,
        const unsigned short* __restrict__ ktb, const unsigned short* __restrict__ xb,
        const float* __restrict__ Wcol, unsigned short* __restrict__ Yt,
        float* __restrict__ rowP) {
    __shared__ unsigned short Pl[3][64 * 64];  // [buf][n][64m] byte-swizzled, 8KB each
    __shared__ float rpl[4][64];
    int b = blockIdx.y;
    int n0 = blockIdx.x * 64;
    int lane = threadIdx.x & 63, w = threadIdx.x >> 6;
    int ms = w >> 1, wn = w & 1;
    int r16 = lane & 15, g = lane >> 4;
    int swz = (r16 & 7) << 4;

    const unsigned short* qbp = qb + ((size_t)b * N_ + n0 + 32 * wn + r16) * 32 + 8 * g;
    bf16x8 qf0 = *(const bf16x8*)(qbp);
    bf16x8 qf1 = *(const bf16x8*)(qbp + 16 * 32);
    const unsigned short* kbp = ktb + ((size_t)b * N_ + 16 * ms + r16) * 32 + 8 * g;
    const unsigned short* xbp = xb + ((size_t)b * C_ + 32 * w + r16) * N_ + 8 * g;
    const float* izp = Wcol + (size_t)b * N_ + 16 * ms + 4 * g;

    char* pwbase = (char*)&Pl[0][0] + (32 * wn + r16) * 128 + ((32 * ms + 8 * g) ^ swz);

    f32x4 acc[4][2];
#pragma unroll
    for (int i = 0; i < 4; ++i)
#pragma unroll
        for (int j = 0; j < 2; ++j) acc[i][j] = (f32x4){0, 0, 0, 0};
    float rp0 = 0.0f, rp1 = 0.0f;

// S for m-step (via KAV,IZV regs) -> exp2*invZ -> rowsum -> P[WJ]
#define S_STEP(KAV, IZV, WJ)                                                          \
    {                                                                                 \
        f32x4 s0 = __builtin_amdgcn_mfma_f32_16x16x32_bf16(KAV, qf0, (f32x4){0,0,0,0}, 0, 0, 0); \
        f32x4 s1 = __builtin_amdgcn_mfma_f32_16x16x32_bf16(KAV, qf1, (f32x4){0,0,0,0}, 0, 0, 0); \
        float p00 = fexp2(s0[0]) * IZV.x, p01 = fexp2(s0[1]) * IZV.y;                 \
        float p02 = fexp2(s0[2]) * IZV.z, p03 = fexp2(s0[3]) * IZV.w;                 \
        float p10 = fexp2(s1[0]) * IZV.x, p11 = fexp2(s1[1]) * IZV.y;                 \
        float p12 = fexp2(s1[2]) * IZV.z, p13 = fexp2(s1[3]) * IZV.w;                 \
        rp0 += p00 + p01 + p02 + p03;                                                 \
        rp1 += p10 + p11 + p12 + p13;                                                 \
        char* pw = pwbase + (WJ) * 8192;                                              \
        *(uint2*)(pw) = make_uint2(                                                   \
            (unsigned)f2bf(p00) | ((unsigned)f2bf(p01) << 16),                        \
            (unsigned)f2bf(p02) | ((unsigned)f2bf(p03) << 16));                       \
        *(uint2*)(pw + 16 * 128) = make_uint2(                                        \
            (unsigned)f2bf(p10) | ((unsigned)f2bf(p11) << 16),                        \
            (unsigned)f2bf(p12) | ((unsigned)f2bf(p13) << 16));                       \
    }

    // prologue: S(0)->P[0], S(1)->P[1]; fill 3-deep queues (ka/iz for t+2, xf for t)
    bf16x8 kt0 = *(const bf16x8*)(kbp);
    bf16x8 kt1 = *(const bf16x8*)(kbp + (size_t)64 * 32);
    float4 it0 = *(const float4*)(izp);
    float4 it1 = *(const float4*)(izp + 64);
    bf16x8 kq0 = *(const bf16x8*)(kbp + (size_t)128 * 32);
    bf16x8 kq1 = *(const bf16x8*)(kbp + (size_t)192 * 32);
    bf16x8 kq2 = *(const bf16x8*)(kbp + (size_t)256 * 32);
    float4 izq0 = *(const float4*)(izp + 128);
    float4 izq1 = *(const float4*)(izp + 192);
    float4 izq2 = *(const float4*)(izp + 256);
    bf16x8 xq0[2][2], xq1[2][2], xq2[2][2];
#pragma unroll
    for (int cs = 0; cs < 2; ++cs)
#pragma unroll
        for (int ks = 0; ks < 2; ++ks) {
            xq0[cs][ks] = *(const bf16x8*)(xbp + (size_t)cs * 16 * N_ + 32 * ks);
            xq1[cs][ks] = *(const bf16x8*)(xbp + (size_t)cs * 16 * N_ + 64 + 32 * ks);
            xq2[cs][ks] = *(const bf16x8*)(xbp + (size_t)cs * 16 * N_ + 128 + 32 * ks);
        }
    S_STEP(kt0, it0, 0);
    S_STEP(kt1, it1, 1);
    LDS_BARRIER();

// body: PV(T) from P[J] x xqJ; S(T+2)->P[WJ] via kqJ/izqJ; reload queues (+3/+5)
#define BODY(T, J, WJ)                                                                \
    {                                                                                 \
        const char* prd = (const char*)&Pl[(J)][0] + r16 * 128;                       \
        bf16x8 pa[4][2];                                                              \
        _Pragma("unroll") for (int ns = 0; ns < 4; ++ns)                              \
            _Pragma("unroll") for (int ks = 0; ks < 2; ++ks)                          \
                pa[ns][ks] = *(const bf16x8*)(prd + ns * 16 * 128 +                   \
                                              ((64 * ks + 16 * g) ^ swz));            \
        if ((T) < 62) S_STEP(kq##J, izq##J, WJ);                                      \
        _Pragma("unroll") for (int ns = 0; ns < 4; ++ns)                              \
            _Pragma("unroll") for (int cs = 0; cs < 2; ++cs)                          \
                _Pragma("unroll") for (int ks = 0; ks < 2; ++ks)                      \
                    acc[ns][cs] = __builtin_amdgcn_mfma_f32_16x16x32_bf16(            \
                        pa[ns][ks], xq##J[cs][ks], acc[ns][cs], 0, 0, 0);             \
        kq##J = *(const bf16x8*)(kbp + (size_t)((T) + 5) * 64 * 32);                  \
        izq##J = *(const float4*)(izp + (size_t)((T) + 5) * 64);                      \
        _Pragma("unroll") for (int cs = 0; cs < 2; ++cs)                              \
            _Pragma("unroll") for (int ks = 0; ks < 2; ++ks)                          \
                xq##J[cs][ks] = *(const bf16x8*)(xbp + (size_t)cs * 16 * N_ +         \
                                                 (size_t)((T) + 3) * 64 + 32 * ks);   \
        LDS_BARRIER();                                                                \
    }

    for (int u = 0; u < 21; ++u) {  // t = 0..62
        int t0 = 3 * u;
        BODY(t0, 0, 2);
        BODY(t0 + 1, 1, 0);
        BODY(t0 + 2, 2, 1);
    }
    {  // tail t = 63: PV only (P[63%3=0], xf(63) sits in xq0)
        const char* prd = (const char*)&Pl[0][0] + r16 * 128;
        bf16x8 pa[4][2];
#pragma unroll
        for (int ns = 0; ns < 4; ++ns)
#pragma unroll
            for (int ks = 0; ks < 2; ++ks)
                pa[ns][ks] = *(const bf16x8*)(prd + ns * 16 * 128 + ((64 * ks + 16 * g) ^ swz));
#pragma unroll
        for (int ns = 0; ns < 4; ++ns)
#pragma unroll
            for (int cs = 0; cs < 2; ++cs)
#pragma unroll
                for (int ks = 0; ks < 2; ++ks)
                    acc[ns][cs] = __builtin_amdgcn_mfma_f32_16x16x32_bf16(
                        pa[ns][ks], xq0[cs][ks], acc[ns][cs], 0, 0, 0);
    }
#undef BODY
#undef S_STEP

    // rowP reduce: sum over g (shfl) then over ms (LDS)
    rp0 += __shfl_xor(rp0, 16); rp0 += __shfl_xor(rp0, 32);
    rp1 += __shfl_xor(rp1, 16); rp1 += __shfl_xor(rp1, 32);
    if (g == 0) {
        rpl[ms][32 * wn + r16] = rp0;
        rpl[ms][32 * wn + 16 + r16] = rp1;
    }
    __syncthreads();
    if (threadIdx.x < 64)
        rowP[(size_t)b * N_ + n0 + threadIdx.x] =
            rpl[0][threadIdx.x] + rpl[1][threadIdx.x] + rpl[2][threadIdx.x] + rpl[3][threadIdx.x];

    // Yt[b][n][cp] bf16 stores (2B scatter, epilogue-only)
#pragma unroll
    for (int ns = 0; ns < 4; ++ns)
#pragma unroll
        for (int cs = 0; cs < 2; ++cs) {
            int cp = 32 * w + 16 * cs + r16;
            f32x4 a = acc[ns][cs];
#pragma unroll
            for (int r = 0; r < 4; ++r) {
                int n = n0 + 16 * ns + 4 * g + r;
                Yt[((size_t)b * N_ + n) * C_ + cp] = f2bf(a[r]);
            }
        }
}

// ---------- k5: out[c][n] = gamma*(Wv·Y[n] + rowP[n]*bv[c]) + x[c][n] -------------
__global__ __launch_bounds__(256) void k5_out(const float* __restrict__ x,
        const unsigned short* __restrict__ wvb, const unsigned short* __restrict__ Yt,
        const float* __restrict__ rowP, const float* __restrict__ bv,
        const float* __restrict__ gamma, float* __restrict__ out) {
    int b = blockIdx.y;
    int n0 = blockIdx.x * 32;
    int lane = threadIdx.x & 63, w = threadIdx.x >> 6;
    int r16 = lane & 15, g = lane >> 4;
    const unsigned short* wvp = wvb + (64 * w + r16) * C_ + 8 * g;
    const unsigned short* ytp = Yt + ((size_t)b * N_ + n0 + r16) * C_ + 8 * g;

    f32x4 acc[4][2];  // [cs][ns]
#pragma unroll
    for (int i = 0; i < 4; ++i)
#pragma unroll
        for (int j = 0; j < 2; ++j) acc[i][j] = (f32x4){0, 0, 0, 0};

#pragma unroll
    for (int kc = 0; kc < 8; ++kc) {
        bf16x8 yf[2];
#pragma unroll
        for (int ns = 0; ns < 2; ++ns)
            yf[ns] = *(const bf16x8*)(ytp + ns * 16 * C_ + kc * 32);
#pragma unroll
        for (int cs = 0; cs < 4; ++cs) {
            bf16x8 wf = *(const bf16x8*)(wvp + cs * 16 * C_ + kc * 32);
#pragma unroll
            for (int ns = 0; ns < 2; ++ns)
                acc[cs][ns] = __builtin_amdgcn_mfma_f32_16x16x32_bf16(
                    wf, yf[ns], acc[cs][ns], 0, 0, 0);
        }
    }
    float gm = gamma[0];
    float rpv[2];
#pragma unroll
    for (int ns = 0; ns < 2; ++ns) rpv[ns] = rowP[(size_t)b * N_ + n0 + 16 * ns + r16];
#pragma unroll
    for (int cs = 0; cs < 4; ++cs) {
        float4 bvv = *(const float4*)(bv + 64 * w + 16 * cs + 4 * g);
        float bva[4] = {bvv.x, bvv.y, bvv.z, bvv.w};
#pragma unroll
        for (int ns = 0; ns < 2; ++ns)
#pragma unroll
            for (int r = 0; r < 4; ++r) {
                int c = 64 * w + 16 * cs + 4 * g + r;
                int n = n0 + 16 * ns + r16;
                size_t idx = ((size_t)b * C_ + c) * N_ + n;
                out[idx] = gm * (acc[cs][ns][r] + rpv[ns] * bva[r]) + x[idx];
            }
    }
}

extern "C" void kernel_launch(void* const* d_in, const int* in_sizes, int n_in,
                              void* d_out, int out_size, void* d_ws, size_t ws_size,
                              hipStream_t stream) {
    const float* x = (const float*)d_in[0];
    const float* Wq = (const float*)d_in[1];
    const float* bq = (const float*)d_in[2];
    const float* Wk = (const float*)d_in[3];
    const float* bk = (const float*)d_in[4];
    const float* Wv = (const float*)d_in[5];
    const float* bv = (const float*)d_in[6];
    const float* gamma = (const float*)d_in[7];
    float* out = (float*)d_out;

    char* ws = (char*)d_ws;
    unsigned short* qb  = (unsigned short*)(ws);                       // 1 MiB
    unsigned short* ktb = (unsigned short*)(ws + (1u << 20));          // 1 MiB
    unsigned short* xb  = (unsigned short*)(ws + (2u << 20));          // 8 MiB
    unsigned short* Yt  = (unsigned short*)(ws + (10u << 20));         // 8 MiB
    float* Wcol = (float*)(ws + (18u << 20));                          // 64 KiB
    float* WqkT = (float*)(ws + (18u << 20) + (1u << 16));             // 64 KiB
    unsigned short* wvb = (unsigned short*)(ws + (18u << 20) + (2u << 16)); // 128 KiB
    float* rowP = (float*)(ws + (18u << 20) + (4u << 16));             // 64 KiB

    k0_wprep<<<320, 256, 0, stream>>>(Wq, Wk, Wv, WqkT, wvb);
    k1_qkx<<<dim3(N_ / 64, B_), 256, 0, stream>>>(x, WqkT, bq, bk, qb, ktb, xb);
    k2_stats<<<dim3(N_ / 64, B_), 512, 0, stream>>>(qb, ktb, Wcol);
    k4_y<<<dim3(N_ / 64, B_), 512, 0, stream>>>(qb, ktb, xb, Wcol, Yt, rowP);
    k5_out<<<dim3(N_ / 32, B_), 256, 0, stream>>>(x, wvb, Yt, rowP, bv, gamma, out);
}